// Round 6
// baseline (392.933 us; speedup 1.0000x reference)
//
#include <hip/hip_runtime.h>

typedef _Float16 h8v __attribute__((ext_vector_type(8)));
typedef _Float16 h4v __attribute__((ext_vector_type(4)));
typedef float    f4v __attribute__((ext_vector_type(4)));

#define MFMA16(a,b,c) __builtin_amdgcn_mfma_f32_16x16x32_f16((a),(b),(c),0,0,0)
#define NEGF (-1e30f)

#define MEM 1000
#define KEY 64
#define VAL 128
#define DIN 512
#define BS  512
#define BQ  65536

// Fragment-major B layouts: element (F,KS,lane,j) at ((F*nKS+KS)*64+lane)*8+j
// holds B[n = F*16 + (lane&15)][k = KS*32 + (lane>>4)*8 + j]  -> every MFMA
// B-fragment load is lane-contiguous (16 B/lane, 1 KB/wave, 8 full lines),
// and (critically for global_load_lds) LINEAR.
//
// SWAPPED-QK (verified R5, absmax unchanged): MFMA16(Kfrag, Qfrag) computes
// P^T with P[query=lane&15][slot = f*16 + quad*4 + r] lane-local. valF's
// k-dim is permuted in prep3 so PV's A-frag is the lane's OWN S values.
//
// R6: R5 spilled (~290 live > 256 cap: WRITE_SIZE 34->86 MB). Fix: (a) qf
// frags stashed in the loop-dead P_s LDS (frees 32 loop-long regs), (b)
// per-tile sequential QK->SM_PV (SA and SB never co-live). Peak ~155 regs.

typedef __attribute__((address_space(1))) const unsigned int guint;
typedef __attribute__((address_space(3))) unsigned int luint;

// async global->LDS, 16 B/lane: LDS gets [uniform l + lane*16B] = g[lane*16B]
__device__ __forceinline__ void gld16(const _Float16* g, _Float16* l)
{
  __builtin_amdgcn_global_load_lds((guint*)g, (luint*)l, 16, 0, 0);
}

__device__ __forceinline__ h8v cvt8(const float* p)
{
  f4v u = *(const f4v*)p;
  f4v v = *(const f4v*)(p + 4);
  h8v a;
  a[0] = (_Float16)u.x; a[1] = (_Float16)u.y; a[2] = (_Float16)u.z; a[3] = (_Float16)u.w;
  a[4] = (_Float16)v.x; a[5] = (_Float16)v.y; a[6] = (_Float16)v.z; a[7] = (_Float16)v.w;
  return a;
}

__device__ __forceinline__ h8v cvt8nt(const float* p)
{
  f4v u = __builtin_nontemporal_load((const f4v*)p);
  f4v v = __builtin_nontemporal_load((const f4v*)(p + 4));
  h8v a;
  a[0] = (_Float16)u.x; a[1] = (_Float16)u.y; a[2] = (_Float16)u.z; a[3] = (_Float16)u.w;
  a[4] = (_Float16)v.x; a[5] = (_Float16)v.y; a[6] = (_Float16)v.z; a[7] = (_Float16)v.w;
  return a;
}

// ---------------------------------------------------------------------------
// prep1: fragment-major weights, Wck = baseW@kpW fused, bcomb, ranks, zero
// ---------------------------------------------------------------------------
__global__ void k_prep1(const float* __restrict__ baseW, const float* __restrict__ base_b,
                        const float* __restrict__ kpW, const float* __restrict__ kp_b,
                        const float* __restrict__ vpW, const float* __restrict__ c1W,
                        const float* __restrict__ c2W, const float* __restrict__ age,
                        _Float16* __restrict__ WTf, float* __restrict__ bcomb,
                        _Float16* __restrict__ vpWt, _Float16* __restrict__ c1F,
                        _Float16* __restrict__ c2F, int* __restrict__ ranks,
                        float* __restrict__ out0)
{
  long id = (long)blockIdx.x * 256 + threadIdx.x;
  if (id < 65536) {                        // WTf: [baseW^T | Wck^T], n=128, k=512 (KS=16)
    int h = (int)id;
    int j = h & 7, lane = (h >> 3) & 63, KS = (h >> 9) & 15, F = h >> 13;
    int n = F * 16 + (lane & 15);
    int k = KS * 32 + ((lane >> 4) << 3) + j;
    float v;
    if (n < 64) v = baseW[(size_t)k * 64 + n];
    else {
      int nn = n - 64;
      const float* br = baseW + (size_t)k * 64;
      float s = 0.f;
      for (int t = 0; t < 64; ++t) s += br[t] * kpW[t * 64 + nn];
      v = s;
    }
    WTf[h] = (_Float16)v;
  } else if (id < 65664) {                 // bcomb
    int i = (int)(id - 65536);
    if (i < 64) bcomb[i] = base_b[i];
    else {
      int n = i - 64;
      float s = kp_b[n];
      for (int t = 0; t < 64; ++t) s += base_b[t] * kpW[t * 64 + n];
      bcomb[i] = s;
    }
  } else if (id < 90240) {                 // c1F: n=128 (F=8), k=192 (KS=6)
    int h = (int)(id - 65664);
    int j = h & 7, lane = (h >> 3) & 63, KS = (h >> 9) % 6, F = (h >> 9) / 6;
    int n = F * 16 + (lane & 15);
    int k = KS * 32 + ((lane >> 4) << 3) + j;
    c1F[h] = (_Float16)c1W[(size_t)k * 128 + n];
  } else if (id < 98432) {                 // c2F: n=64 (F=4), k=128 (KS=4)
    int h = (int)(id - 90240);
    int j = h & 7, lane = (h >> 3) & 63, KS = (h >> 9) & 3, F = h >> 11;
    int n = F * 16 + (lane & 15);
    int k = KS * 32 + ((lane >> 4) << 3) + j;
    c2F[h] = (_Float16)c2W[(size_t)k * 64 + n];
  } else if (id < 114816) {                // vpWt[n][k] (row-major transposed, prep2 only)
    long i = id - 98432;
    int n = (int)(i >> 7), k = (int)(i & 127);
    vpWt[i] = (_Float16)vpW[(size_t)k * 128 + n];
  } else if (id < 115816) {                // stable ranks (lax.top_k order)
    int jx = (int)(id - 114816);
    float aj = age[jx];
    int r = 0;
    for (int i2 = 0; i2 < MEM; ++i2) {
      float ai = age[i2];
      r += (ai > aj) || (ai == aj && i2 < jx);
    }
    ranks[jx] = r;
  } else if (id == 115816) {
    *out0 = 0.f;
  }
}

// ---------------------------------------------------------------------------
// prep2: pkeys = sx@Wck + bck ; pvals = sy@vpW + vp_b
// ---------------------------------------------------------------------------
__global__ __launch_bounds__(64) void k_prep2(
    const float* __restrict__ sx, const float* __restrict__ sy,
    const _Float16* __restrict__ WTf, const float* __restrict__ bcomb,
    const _Float16* __restrict__ vpWt, const float* __restrict__ vp_b,
    float* __restrict__ pkeys, float* __restrict__ pvals)
{
  const int lane = threadIdx.x, quad = lane >> 4, l15 = lane & 15;
  const f4v fz = {0.f, 0.f, 0.f, 0.f};
  if (blockIdx.x < 32) {
    const int m0 = blockIdx.x * 16;
    f4v acc[4];
    #pragma unroll
    for (int f = 0; f < 4; ++f) acc[f] = fz;
    const float* xr = sx + (size_t)(m0 + l15) * DIN;
    #pragma unroll 4
    for (int ks = 0; ks < 16; ++ks) {
      int k0 = ks * 32 + quad * 8;
      h8v a = cvt8(xr + k0);
      #pragma unroll
      for (int f = 0; f < 4; ++f) {
        h8v b = *(const h8v*)(WTf + (size_t)((((4 + f) * 16) + ks) * 64 + lane) * 8);
        acc[f] = MFMA16(a, b, acc[f]);
      }
    }
    #pragma unroll
    for (int f = 0; f < 4; ++f) {
      int col = f * 16 + l15;
      float bb = bcomb[64 + col];
      #pragma unroll
      for (int r = 0; r < 4; ++r)
        pkeys[(size_t)(m0 + quad * 4 + r) * KEY + col] = acc[f][r] + bb;
    }
  } else {
    const int m0 = (blockIdx.x - 32) * 16;
    f4v acc[8];
    #pragma unroll
    for (int f = 0; f < 8; ++f) acc[f] = fz;
    const float* yr = sy + (size_t)(m0 + l15) * VAL;
    #pragma unroll
    for (int ks = 0; ks < 4; ++ks) {
      int k0 = ks * 32 + quad * 8;
      h8v a = cvt8(yr + k0);
      #pragma unroll
      for (int f = 0; f < 8; ++f) {
        h8v b = *(const h8v*)(vpWt + (size_t)(f * 16 + l15) * 128 + k0);
        acc[f] = MFMA16(a, b, acc[f]);
      }
    }
    #pragma unroll
    for (int f = 0; f < 8; ++f) {
      int col = f * 16 + l15;
      float bb = vp_b[col];
      #pragma unroll
      for (int r = 0; r < 4; ++r)
        pvals[(size_t)(m0 + quad * 4 + r) * VAL + col] = acc[f][r] + bb;
    }
  }
}

// ---------------------------------------------------------------------------
// prep3: scatter memory into fragment-major keysF / valF (zero-padded)
// keysF: n=1024 slots (F=64), k=KEY 64 (KS=2)  -- unchanged
// valF : n=VAL 128 (F=8),     k=1024 slots (KS=32), k-dim PERMUTED per
//        32-slot step so PV A-frags are lane-local under swapped QK:
//        frag pos (quad,j) holds slot KS*32 + (j>>2)*16 + quad*4 + (j&3).
// ---------------------------------------------------------------------------
__global__ void k_prep3(const int* __restrict__ ranks, const float* __restrict__ pk,
                        const float* __restrict__ pv, const float* __restrict__ memK,
                        const float* __restrict__ memV,
                        _Float16* __restrict__ keysF, _Float16* __restrict__ valF)
{
  int id = blockIdx.x * 256 + threadIdx.x;
  if (id < 65536) {
    int j = id & 7, lane = (id >> 3) & 63, KS = (id >> 9) & 1, F = id >> 10;
    int n = F * 16 + (lane & 15);                  // mem slot
    int k = KS * 32 + ((lane >> 4) << 3) + j;      // key col
    float v = 0.f;
    if (n < MEM) {
      int rk = ranks[n];
      v = (rk < BS) ? pk[(size_t)rk * KEY + k] : memK[(size_t)n * KEY + k];
    }
    keysF[id] = (_Float16)v;
  } else {
    int h = id - 65536;
    int j = h & 7, lane = (h >> 3) & 63, KS = (h >> 9) & 31, F = h >> 14;
    int nv = F * 16 + (lane & 15);                 // val col
    // permuted slot within the 32-slot k-step (see header comment)
    int jm = KS * 32 + ((j >> 2) << 4) + (((lane >> 4)) << 2) + (j & 3);
    float v = 0.f;
    if (jm < MEM) {
      int rk = ranks[jm];
      v = (rk < BS) ? pv[(size_t)rk * VAL + nv] : memV[(size_t)jm * VAL + nv];
    }
    valF[h] = (_Float16)v;
  }
}

// ---------------------------------------------------------------------------
// fused: features + attention + controller, 32 queries/wave (tiles A,B),
// 8 waves/block (512 thr), grid 256 -> 1 block/CU, one round.
// Swapped-QK register softmax (R5) + spill fix (R6): qf stash in loop-dead
// P_s LDS, sequential per-tile SM_PV so SA/SB never co-live.
// ---------------------------------------------------------------------------

// softmax + PV for one tile, everything in registers.
#define SM_PV(S, rm, rl, O, Vc, c)                                          \
  {                                                                         \
    float cm = NEGF;                                                        \
    _Pragma("unroll")                                                       \
    for (int f = 0; f < 8; ++f) {                                           \
      const int sb = (c) * 128 + f * 16 + quad * 4;                         \
      _Pragma("unroll")                                                     \
      for (int r = 0; r < 4; ++r) {                                         \
        float s = (sb + r < MEM) ? S[f][r] : NEGF;                          \
        S[f][r] = s;                                                        \
        cm = fmaxf(cm, s);                                                  \
      }                                                                     \
    }                                                                       \
    cm = fmaxf(cm, __shfl_xor(cm, 16));                                     \
    cm = fmaxf(cm, __shfl_xor(cm, 32));                                     \
    float mn = fmaxf(rm, cm);                                               \
    float al = __expf(rm - mn);                                             \
    rm = mn;                                                                \
    float psl = 0.f;                                                        \
    _Pragma("unroll")                                                       \
    for (int f = 0; f < 8; ++f)                                             \
      _Pragma("unroll")                                                     \
      for (int r = 0; r < 4; ++r) {                                         \
        float p = __expf(S[f][r] - mn);                                     \
        S[f][r] = p;                                                        \
        psl += p;                                                           \
      }                                                                     \
    rl = rl * al + psl;                                                     \
    float alO[4];                                                           \
    _Pragma("unroll")                                                       \
    for (int r = 0; r < 4; ++r) alO[r] = __shfl(al, quad * 4 + r);          \
    _Pragma("unroll")                                                       \
    for (int v = 0; v < 8; ++v)                                             \
      _Pragma("unroll")                                                     \
      for (int r = 0; r < 4; ++r) O[v][r] *= alO[r];                        \
    _Pragma("unroll")                                                       \
    for (int ks = 0; ks < 4; ++ks) {                                        \
      h8v a;                                                                \
      _Pragma("unroll")                                                     \
      for (int e = 0; e < 4; ++e) {                                         \
        a[e]     = (_Float16)S[2 * ks][e];                                  \
        a[e + 4] = (_Float16)S[2 * ks + 1][e];                              \
      }                                                                     \
      _Pragma("unroll")                                                     \
      for (int v = 0; v < 8; ++v) {                                         \
        h8v b = *(const h8v*)(Vc + (size_t)(v * 4 + ks) * 512 + lane * 8);  \
        O[v] = MFMA16(a, b, O[v]);                                          \
      }                                                                     \
    }                                                                       \
  }

__global__ __launch_bounds__(512, 2) void k_fused(
    const float* __restrict__ qx, const float* __restrict__ qy,
    const _Float16* __restrict__ WTf, const float* __restrict__ bcomb,
    const float* __restrict__ c1_b, const float* __restrict__ c2_b,
    const float* __restrict__ c3W, const float* __restrict__ c3b,
    const _Float16* __restrict__ c1F, const _Float16* __restrict__ c2F,
    const _Float16* __restrict__ keysF, const _Float16* __restrict__ valF,
    float* __restrict__ dout)
{
  // LDS union, 148 KB total:
  //  phase 1: [0,131072) = WTsh (128 KB); per-wave tbuf at wid*4352 (34 KB)
  //  phase 2: K[2] at 0 (2x16 KB), V[2] at 32768 (2x32 KB), Pwk at 98304 (52 KB)
  __shared__ __align__(16) char smem[151552];
  _Float16* const WTsh = (_Float16*)smem;
  _Float16* const K0   = (_Float16*)smem;                 // 8192 halves
  _Float16* const K1   = (_Float16*)(smem + 16384);
  _Float16* const V0   = (_Float16*)(smem + 32768);       // 16384 halves
  _Float16* const V1   = (_Float16*)(smem + 65536);

  const int tid  = threadIdx.x;
  const int wid  = tid >> 6;
  const int lane = tid & 63;
  const int quad = lane >> 4;
  const int l15  = lane & 15;

  _Float16* const P_s  = (_Float16*)(smem + 98304 + wid * 6656);  // 2176 halves
  _Float16* const h2_s = P_s + 2176;                              // 1152 halves

  const int tA  = blockIdx.x * 16 + wid * 2;   // two query tiles per wave
  const int q0A = tA * 16;
  const int q0B = q0A + 16;

  float* out_pred = dout + 1;
  float* out_ret  = dout + 1 + BQ;
  const f4v fz = {0.f, 0.f, 0.f, 0.f};

  // ================= phase 1: features =================
  #pragma unroll
  for (int i = 0; i < 16; ++i) {
    const int t = wid * 16 + i;
    gld16(WTf + (size_t)t * 512 + lane * 8, WTsh + t * 512);
  }
  asm volatile("s_waitcnt vmcnt(0)" ::: "memory");
  __syncthreads();

  f4v accA[8], accB[8];
  #pragma unroll
  for (int f = 0; f < 8; ++f) { accA[f] = fz; accB[f] = fz; }
  const float* xrA = qx + (size_t)(q0A + l15) * DIN;
  const float* xrB = qx + (size_t)(q0B + l15) * DIN;

  #pragma unroll 4
  for (int ks = 0; ks < 16; ++ks) {
    const int k0 = ks * 32 + quad * 8;
    h8v aA = cvt8nt(xrA + k0);
    h8v aB = cvt8nt(xrB + k0);
    #pragma unroll
    for (int f = 0; f < 8; ++f) {
      h8v b = *(const h8v*)(WTsh + (size_t)((f * 16 + ks) * 64 + lane) * 8);
      accA[f] = MFMA16(aA, b, accA[f]);
      accB[f] = MFMA16(aB, b, accB[f]);
    }
  }
  __syncthreads();   // all waves done reading WTsh -> reuse as scratch

  // C-layout -> A-frag registers via per-wave LDS transpose.
  // qf frags go to the P_s stash (loop-dead LDS), NOT loop-long registers.
  _Float16* tbuf = (_Float16*)(smem + wid * 4352);  // 2176 halves
  h8v pq0A, pq1A, pq0B, pq1B;
  {
    #pragma unroll
    for (int f = 0; f < 8; ++f) {
      float bb = bcomb[f * 16 + l15];
      #pragma unroll
      for (int r = 0; r < 4; ++r)
        tbuf[(quad * 4 + r) * 136 + f * 16 + l15] = (_Float16)(accA[f][r] + bb);
    }
    h8v qf0A = *(const h8v*)&tbuf[l15 * 136 +  0 + quad * 8];
    h8v qf1A = *(const h8v*)&tbuf[l15 * 136 + 32 + quad * 8];
    pq0A = *(const h8v*)&tbuf[l15 * 136 + 64 + quad * 8];
    pq1A = *(const h8v*)&tbuf[l15 * 136 + 96 + quad * 8];
    *(h8v*)&P_s[0 * 512 + lane * 8] = qf0A;
    *(h8v*)&P_s[1 * 512 + lane * 8] = qf1A;
    #pragma unroll
    for (int f = 0; f < 8; ++f) {
      float bb = bcomb[f * 16 + l15];
      #pragma unroll
      for (int r = 0; r < 4; ++r)
        tbuf[(quad * 4 + r) * 136 + f * 16 + l15] = (_Float16)(accB[f][r] + bb);
    }
    h8v qf0B = *(const h8v*)&tbuf[l15 * 136 +  0 + quad * 8];
    h8v qf1B = *(const h8v*)&tbuf[l15 * 136 + 32 + quad * 8];
    pq0B = *(const h8v*)&tbuf[l15 * 136 + 64 + quad * 8];
    pq1B = *(const h8v*)&tbuf[l15 * 136 + 96 + quad * 8];
    *(h8v*)&P_s[2 * 512 + lane * 8] = qf0B;
    *(h8v*)&P_s[3 * 512 + lane * 8] = qf1B;
  }
  __syncthreads();   // scratch reads done -> K/V staging may overwrite

  // ================= phase 2: attention =================
  // stage chunk 0 (8 waves: 2 K-tiles + 4 V-tiles each)
  #pragma unroll
  for (int i = 0; i < 2; ++i) {
    const int t = wid * 2 + i;
    gld16(keysF + (size_t)t * 512 + lane * 8, K0 + t * 512);
  }
  #pragma unroll
  for (int i = 0; i < 4; ++i) {
    const int t = wid * 4 + i;
    const int v = t >> 2, sub = t & 3;
    gld16(valF + ((size_t)(v * 32 + sub)) * 512 + lane * 8,
          V0 + (v * 4 + sub) * 512);
  }
  asm volatile("s_waitcnt vmcnt(0)" ::: "memory");
  __syncthreads();

  float rmA = NEGF, rlA = 0.f, rmB = NEGF, rlB = 0.f;   // scalars (query=l15)
  f4v OA[8], OB[8];
  #pragma unroll
  for (int v = 0; v < 8; ++v) { OA[v] = fz; OB[v] = fz; }

  #pragma unroll 1
  for (int c = 0; c < 8; ++c) {
    const int cur = c & 1;
    _Float16* const Kc = cur ? K1 : K0;
    _Float16* const Vc = cur ? V1 : V0;
    _Float16* const Kn = cur ? K0 : K1;
    _Float16* const Vn = cur ? V0 : V1;

    // prefetch next chunk (or c1F into the dying buffer pair at c==7)
    if (c < 7) {
      const int nc = c + 1;
      const _Float16* kc = keysF + (size_t)nc * 8192;
      #pragma unroll
      for (int i = 0; i < 2; ++i) {
        const int t = wid * 2 + i;
        gld16(kc + (size_t)t * 512 + lane * 8, Kn + t * 512);
      }
      #pragma unroll
      for (int i = 0; i < 4; ++i) {
        const int t = wid * 4 + i;
        const int v = t >> 2, sub = t & 3;
        gld16(valF + ((size_t)(v * 32 + nc * 4 + sub)) * 512 + lane * 8,
              Vn + (v * 4 + sub) * 512);
      }
    } else {
      // c1F: 48 x 1 KB tiles -> K0(16) + V0(32); 6 tiles per wave
      #pragma unroll
      for (int i = 0; i < 6; ++i) {
        const int t = wid * 6 + i;
        _Float16* dst = (t < 16) ? (K0 + t * 512) : (V0 + (t - 16) * 512);
        gld16(c1F + (size_t)t * 512 + lane * 8, dst);
      }
    }

    // ---- tile A: QK^T (swapped) -> softmax + PV (register-only) ----
    {
      f4v SA[8];
      #pragma unroll
      for (int f = 0; f < 8; ++f) SA[f] = fz;
      #pragma unroll
      for (int f = 0; f < 8; ++f) {
        h8v b0 = *(const h8v*)(Kc + (size_t)(f * 2 + 0) * 512 + lane * 8);
        h8v b1 = *(const h8v*)(Kc + (size_t)(f * 2 + 1) * 512 + lane * 8);
        SA[f] = MFMA16(b0, pq0A, SA[f]);
        SA[f] = MFMA16(b1, pq1A, SA[f]);
      }
      SM_PV(SA, rmA, rlA, OA, Vc, c)
    }

    // ---- tile B (SA dead by construction -> no pressure overlap) ----
    {
      f4v SB[8];
      #pragma unroll
      for (int f = 0; f < 8; ++f) SB[f] = fz;
      #pragma unroll
      for (int f = 0; f < 8; ++f) {
        h8v b0 = *(const h8v*)(Kc + (size_t)(f * 2 + 0) * 512 + lane * 8);
        h8v b1 = *(const h8v*)(Kc + (size_t)(f * 2 + 1) * 512 + lane * 8);
        SB[f] = MFMA16(b0, pq0B, SB[f]);
        SB[f] = MFMA16(b1, pq1B, SB[f]);
      }
      SM_PV(SB, rmB, rlB, OB, Vc, c)
    }

    // drain next-chunk staging + protect buffer reuse across all 8 waves
    asm volatile("s_waitcnt vmcnt(0)" ::: "memory");
    __syncthreads();
  }

  // ---- final denominators: reduce over quads, redistribute to O layout ----
  rlA += __shfl_xor(rlA, 16); rlA += __shfl_xor(rlA, 32);
  rlB += __shfl_xor(rlB, 16); rlB += __shfl_xor(rlB, 32);
  float rlOA[4], rlOB[4];
  #pragma unroll
  for (int r = 0; r < 4; ++r) {
    rlOA[r] = __shfl(rlA, quad * 4 + r);
    rlOB[r] = __shfl(rlB, quad * 4 + r);
  }

  // reload stashed qf BEFORE ret writes clobber P_s
  h8v qf0A = *(const h8v*)&P_s[0 * 512 + lane * 8];
  h8v qf1A = *(const h8v*)&P_s[1 * 512 + lane * 8];
  h8v qf0B = *(const h8v*)&P_s[2 * 512 + lane * 8];
  h8v qf1B = *(const h8v*)&P_s[3 * 512 + lane * 8];

  // ================= phase 3: epilogue (per tile) =================
  #pragma unroll
  for (int par = 0; par < 2; ++par) {
    const int q0 = par ? q0B : q0A;
    float* rlO = par ? rlOB : rlOA;
    f4v*   O   = par ? OB  : OA;
    const h8v qf0 = par ? qf0B : qf0A;
    const h8v qf1 = par ? qf1B : qf1A;

    // retrieved -> LDS fp16
    #pragma unroll
    for (int v = 0; v < 8; ++v)
      #pragma unroll
      for (int r = 0; r < 4; ++r)
        P_s[(quad * 4 + r) * 136 + v * 16 + l15] = (_Float16)(O[v][r] / rlO[r]);

    // contiguous nt stores: 8 iters x (64 lanes x 16 B)
    #pragma unroll
    for (int it = 0; it < 8; ++it) {
      int flat = it * 256 + lane * 4;
      int row = flat >> 7, col = flat & 127;
      h4v t = *(const h4v*)&P_s[row * 136 + col];
      f4v o;
      o.x = (float)t[0]; o.y = (float)t[1]; o.z = (float)t[2]; o.w = (float)t[3];
      __builtin_nontemporal_store(o, (f4v*)(out_ret + (size_t)q0 * VAL + flat));
    }

    // c1: relu([qf|ret] @ c1_W + b); b-frags from LDS (staged at c==7)
    {
      f4v H[8];
      #pragma unroll
      for (int f = 0; f < 8; ++f) H[f] = fz;
      #pragma unroll
      for (int ks = 0; ks < 6; ++ks) {
        const int k0 = ks * 32;
        h8v a = (ks == 0) ? qf0 : (ks == 1) ? qf1
                 : *(const h8v*)&P_s[l15 * 136 + (k0 - 64) + quad * 8];
        #pragma unroll
        for (int f = 0; f < 8; ++f) {
          const int t = f * 6 + ks;
          const _Float16* bp = (t < 16) ? (K0 + (size_t)t * 512)
                                        : (V0 + (size_t)(t - 16) * 512);
          h8v b = *(const h8v*)(bp + lane * 8);
          H[f] = MFMA16(a, b, H[f]);
        }
      }
      #pragma unroll
      for (int f = 0; f < 8; ++f) {
        float bb = c1_b[f * 16 + l15];
        #pragma unroll
        for (int r = 0; r < 4; ++r)
          P_s[(quad * 4 + r) * 136 + f * 16 + l15] =
              (_Float16)fmaxf(0.f, H[f][r] + bb);
      }
    }

    // c2: relu(h1 @ c2_W + b) -> h2
    {
      f4v G[4];
      #pragma unroll
      for (int f = 0; f < 4; ++f) G[f] = fz;
      #pragma unroll
      for (int ks = 0; ks < 4; ++ks) {
        h8v a = *(const h8v*)&P_s[l15 * 136 + ks * 32 + quad * 8];
        #pragma unroll
        for (int f = 0; f < 4; ++f) {
          h8v b = *(const h8v*)(c2F + (size_t)(f * 4 + ks) * 512 + lane * 8);
          G[f] = MFMA16(a, b, G[f]);
        }
      }
      #pragma unroll
      for (int f = 0; f < 4; ++f) {
        float bb = c2_b[f * 16 + l15];
        #pragma unroll
        for (int r = 0; r < 4; ++r)
          h2_s[(quad * 4 + r) * 72 + f * 16 + l15] =
              (_Float16)fmaxf(0.f, G[f][r] + bb);
      }
    }

    // c3 + loss (4 lanes per query row)
    float lsum;
    {
      const int prow = lane >> 2, pj = lane & 3;
      float s = 0.f;
      #pragma unroll
      for (int k = 0; k < 16; ++k) {
        int kk = pj * 16 + k;
        s += (float)h2_s[prow * 72 + kk] * c3W[kk];
      }
      s += __shfl_xor(s, 1);
      s += __shfl_xor(s, 2);
      float pred = s + c3b[0];
      float diff = pred - qy[q0 + prow];
      if (pj == 0) out_pred[q0 + prow] = pred;
      lsum = diff * diff;                      // each row counted 4x
    }
    #pragma unroll
    for (int m = 1; m < 64; m <<= 1) lsum += __shfl_xor(lsum, m);
    if (lane == 0) atomicAdd(dout, lsum * (1.0f / (4.0f * (float)BQ)));
  }
}

// ---------------------------------------------------------------------------
extern "C" void kernel_launch(void* const* d_in, const int* in_sizes, int n_in,
                              void* d_out, int out_size, void* d_ws, size_t ws_size,
                              hipStream_t stream)
{
  const float* support_x = (const float*)d_in[0];
  const float* support_y = (const float*)d_in[1];
  const float* query_x   = (const float*)d_in[2];
  const float* query_y   = (const float*)d_in[3];
  const float* base_W    = (const float*)d_in[4];
  const float* base_b    = (const float*)d_in[5];
  const float* kp_W      = (const float*)d_in[6];
  const float* kp_b      = (const float*)d_in[7];
  const float* vp_W      = (const float*)d_in[8];
  const float* vp_b      = (const float*)d_in[9];
  const float* mem_keys  = (const float*)d_in[10];
  const float* mem_vals  = (const float*)d_in[11];
  const float* mem_age   = (const float*)d_in[12];
  const float* c1_W      = (const float*)d_in[13];
  const float* c1_b      = (const float*)d_in[14];
  const float* c2_W      = (const float*)d_in[15];
  const float* c2_b      = (const float*)d_in[16];
  const float* c3_W      = (const float*)d_in[17];
  const float* c3_b      = (const float*)d_in[18];

  char* w = (char*)d_ws;                        // ~1 MB used
  _Float16* WTf   = (_Float16*)(w + 0);         // 128 KB fragment-major
  _Float16* vpWt  = (_Float16*)(w + 131072);    // 32 KB
  _Float16* c1F   = (_Float16*)(w + 163840);    // 48 KB fragment-major
  _Float16* c2F   = (_Float16*)(w + 212992);    // 16 KB fragment-major
  float*    bcomb = (float*)   (w + 229376);    // 512 B
  int*      ranks = (int*)     (w + 229888);    // 4 KB
  float*    pkeys = (float*)   (w + 233984);    // 128 KB
  float*    pvals = (float*)   (w + 365056);    // 256 KB
  _Float16* keysF = (_Float16*)(w + 627200);    // 128 KB fragment-major
  _Float16* valF  = (_Float16*)(w + 758272);    // 256 KB fragment-major

  float* out = (float*)d_out;

  hipLaunchKernelGGL(k_prep1, dim3(453), dim3(256), 0, stream,
                     base_W, base_b, kp_W, kp_b, vp_W, c1_W, c2_W, mem_age,
                     WTf, bcomb, vpWt, c1F, c2F, ranks, out);
  hipLaunchKernelGGL(k_prep2, dim3(64), dim3(64), 0, stream,
                     support_x, support_y, WTf, bcomb, vpWt, vp_b, pkeys, pvals);
  hipLaunchKernelGGL(k_prep3, dim3(768), dim3(256), 0, stream,
                     ranks, pkeys, pvals, mem_keys, mem_vals, keysF, valF);
  hipLaunchKernelGGL(k_fused, dim3(BQ / 256), dim3(512), 0, stream,
                     query_x, query_y, WTf, bcomb, c1_b, c2_b, c3_W, c3_b,
                     c1F, c2F, keysF, valF, out);
}

// Round 7
// 362.953 us; speedup vs baseline: 1.0826x; 1.0826x over previous
//
#include <hip/hip_runtime.h>

typedef _Float16 h8v __attribute__((ext_vector_type(8)));
typedef _Float16 h4v __attribute__((ext_vector_type(4)));
typedef float    f4v __attribute__((ext_vector_type(4)));

#define MFMA16(a,b,c) __builtin_amdgcn_mfma_f32_16x16x32_f16((a),(b),(c),0,0,0)
#define NEGF (-1e30f)

#define MEM 1000
#define KEY 64
#define VAL 128
#define DIN 512
#define BS  512
#define BQ  65536

// Fragment-major B layouts: element (F,KS,lane,j) at ((F*nKS+KS)*64+lane)*8+j
// holds B[n = F*16 + (lane&15)][k = KS*32 + (lane>>4)*8 + j]  -> every MFMA
// B-fragment load is lane-contiguous (16 B/lane, 1 KB/wave), and LINEAR for
// global_load_lds.
//
// SWAPPED-QK (verified R5, absmax unchanged): MFMA16(Kfrag, Qfrag) computes
// P^T with P[query=lane&15][slot = f*16 + quad*4 + r] lane-local. valF's
// k-dim is permuted in prep3 so PV's A-frag is the lane's OWN S values.
//
// R7: R5/R6 both spilled (WRITE_SIZE 86/202 MB phantom) because 2 tiles/wave
// persistent state + transient S exceeds the allocator's ~128 arch-VGPR
// split. Fix: ONE tile/wave (16 q/wave), grid 512 (two 1-block/CU rounds).
// Peak live ~100 regs -> no spill. Keeps fusion + register softmax.

typedef __attribute__((address_space(1))) const unsigned int guint;
typedef __attribute__((address_space(3))) unsigned int luint;

// async global->LDS, 16 B/lane: LDS gets [uniform l + lane*16B] = g[lane*16B]
__device__ __forceinline__ void gld16(const _Float16* g, _Float16* l)
{
  __builtin_amdgcn_global_load_lds((guint*)g, (luint*)l, 16, 0, 0);
}

__device__ __forceinline__ h8v cvt8(const float* p)
{
  f4v u = *(const f4v*)p;
  f4v v = *(const f4v*)(p + 4);
  h8v a;
  a[0] = (_Float16)u.x; a[1] = (_Float16)u.y; a[2] = (_Float16)u.z; a[3] = (_Float16)u.w;
  a[4] = (_Float16)v.x; a[5] = (_Float16)v.y; a[6] = (_Float16)v.z; a[7] = (_Float16)v.w;
  return a;
}

__device__ __forceinline__ h8v cvt8nt(const float* p)
{
  f4v u = __builtin_nontemporal_load((const f4v*)p);
  f4v v = __builtin_nontemporal_load((const f4v*)(p + 4));
  h8v a;
  a[0] = (_Float16)u.x; a[1] = (_Float16)u.y; a[2] = (_Float16)u.z; a[3] = (_Float16)u.w;
  a[4] = (_Float16)v.x; a[5] = (_Float16)v.y; a[6] = (_Float16)v.z; a[7] = (_Float16)v.w;
  return a;
}

// ---------------------------------------------------------------------------
// prep1: fragment-major weights, Wck = baseW@kpW fused, bcomb, ranks, zero
// ---------------------------------------------------------------------------
__global__ void k_prep1(const float* __restrict__ baseW, const float* __restrict__ base_b,
                        const float* __restrict__ kpW, const float* __restrict__ kp_b,
                        const float* __restrict__ vpW, const float* __restrict__ c1W,
                        const float* __restrict__ c2W, const float* __restrict__ age,
                        _Float16* __restrict__ WTf, float* __restrict__ bcomb,
                        _Float16* __restrict__ vpWt, _Float16* __restrict__ c1F,
                        _Float16* __restrict__ c2F, int* __restrict__ ranks,
                        float* __restrict__ out0)
{
  long id = (long)blockIdx.x * 256 + threadIdx.x;
  if (id < 65536) {                        // WTf: [baseW^T | Wck^T], n=128, k=512 (KS=16)
    int h = (int)id;
    int j = h & 7, lane = (h >> 3) & 63, KS = (h >> 9) & 15, F = h >> 13;
    int n = F * 16 + (lane & 15);
    int k = KS * 32 + ((lane >> 4) << 3) + j;
    float v;
    if (n < 64) v = baseW[(size_t)k * 64 + n];
    else {
      int nn = n - 64;
      const float* br = baseW + (size_t)k * 64;
      float s = 0.f;
      for (int t = 0; t < 64; ++t) s += br[t] * kpW[t * 64 + nn];
      v = s;
    }
    WTf[h] = (_Float16)v;
  } else if (id < 65664) {                 // bcomb
    int i = (int)(id - 65536);
    if (i < 64) bcomb[i] = base_b[i];
    else {
      int n = i - 64;
      float s = kp_b[n];
      for (int t = 0; t < 64; ++t) s += base_b[t] * kpW[t * 64 + n];
      bcomb[i] = s;
    }
  } else if (id < 90240) {                 // c1F: n=128 (F=8), k=192 (KS=6)
    int h = (int)(id - 65664);
    int j = h & 7, lane = (h >> 3) & 63, KS = (h >> 9) % 6, F = (h >> 9) / 6;
    int n = F * 16 + (lane & 15);
    int k = KS * 32 + ((lane >> 4) << 3) + j;
    c1F[h] = (_Float16)c1W[(size_t)k * 128 + n];
  } else if (id < 98432) {                 // c2F: n=64 (F=4), k=128 (KS=4)
    int h = (int)(id - 90240);
    int j = h & 7, lane = (h >> 3) & 63, KS = (h >> 9) & 3, F = h >> 11;
    int n = F * 16 + (lane & 15);
    int k = KS * 32 + ((lane >> 4) << 3) + j;
    c2F[h] = (_Float16)c2W[(size_t)k * 64 + n];
  } else if (id < 114816) {                // vpWt[n][k] (row-major transposed, prep2 only)
    long i = id - 98432;
    int n = (int)(i >> 7), k = (int)(i & 127);
    vpWt[i] = (_Float16)vpW[(size_t)k * 128 + n];
  } else if (id < 115816) {                // stable ranks (lax.top_k order)
    int jx = (int)(id - 114816);
    float aj = age[jx];
    int r = 0;
    for (int i2 = 0; i2 < MEM; ++i2) {
      float ai = age[i2];
      r += (ai > aj) || (ai == aj && i2 < jx);
    }
    ranks[jx] = r;
  } else if (id == 115816) {
    *out0 = 0.f;
  }
}

// ---------------------------------------------------------------------------
// prep2: pkeys = sx@Wck + bck ; pvals = sy@vpW + vp_b
// ---------------------------------------------------------------------------
__global__ __launch_bounds__(64) void k_prep2(
    const float* __restrict__ sx, const float* __restrict__ sy,
    const _Float16* __restrict__ WTf, const float* __restrict__ bcomb,
    const _Float16* __restrict__ vpWt, const float* __restrict__ vp_b,
    float* __restrict__ pkeys, float* __restrict__ pvals)
{
  const int lane = threadIdx.x, quad = lane >> 4, l15 = lane & 15;
  const f4v fz = {0.f, 0.f, 0.f, 0.f};
  if (blockIdx.x < 32) {
    const int m0 = blockIdx.x * 16;
    f4v acc[4];
    #pragma unroll
    for (int f = 0; f < 4; ++f) acc[f] = fz;
    const float* xr = sx + (size_t)(m0 + l15) * DIN;
    #pragma unroll 4
    for (int ks = 0; ks < 16; ++ks) {
      int k0 = ks * 32 + quad * 8;
      h8v a = cvt8(xr + k0);
      #pragma unroll
      for (int f = 0; f < 4; ++f) {
        h8v b = *(const h8v*)(WTf + (size_t)((((4 + f) * 16) + ks) * 64 + lane) * 8);
        acc[f] = MFMA16(a, b, acc[f]);
      }
    }
    #pragma unroll
    for (int f = 0; f < 4; ++f) {
      int col = f * 16 + l15;
      float bb = bcomb[64 + col];
      #pragma unroll
      for (int r = 0; r < 4; ++r)
        pkeys[(size_t)(m0 + quad * 4 + r) * KEY + col] = acc[f][r] + bb;
    }
  } else {
    const int m0 = (blockIdx.x - 32) * 16;
    f4v acc[8];
    #pragma unroll
    for (int f = 0; f < 8; ++f) acc[f] = fz;
    const float* yr = sy + (size_t)(m0 + l15) * VAL;
    #pragma unroll
    for (int ks = 0; ks < 4; ++ks) {
      int k0 = ks * 32 + quad * 8;
      h8v a = cvt8(yr + k0);
      #pragma unroll
      for (int f = 0; f < 8; ++f) {
        h8v b = *(const h8v*)(vpWt + (size_t)(f * 16 + l15) * 128 + k0);
        acc[f] = MFMA16(a, b, acc[f]);
      }
    }
    #pragma unroll
    for (int f = 0; f < 8; ++f) {
      int col = f * 16 + l15;
      float bb = vp_b[col];
      #pragma unroll
      for (int r = 0; r < 4; ++r)
        pvals[(size_t)(m0 + quad * 4 + r) * VAL + col] = acc[f][r] + bb;
    }
  }
}

// ---------------------------------------------------------------------------
// prep3: scatter memory into fragment-major keysF / valF (zero-padded)
// keysF: n=1024 slots (F=64), k=KEY 64 (KS=2)  -- unchanged
// valF : n=VAL 128 (F=8),     k=1024 slots (KS=32), k-dim PERMUTED per
//        32-slot step so PV A-frags are lane-local under swapped QK:
//        frag pos (quad,j) holds slot KS*32 + (j>>2)*16 + quad*4 + (j&3).
// ---------------------------------------------------------------------------
__global__ void k_prep3(const int* __restrict__ ranks, const float* __restrict__ pk,
                        const float* __restrict__ pv, const float* __restrict__ memK,
                        const float* __restrict__ memV,
                        _Float16* __restrict__ keysF, _Float16* __restrict__ valF)
{
  int id = blockIdx.x * 256 + threadIdx.x;
  if (id < 65536) {
    int j = id & 7, lane = (id >> 3) & 63, KS = (id >> 9) & 1, F = id >> 10;
    int n = F * 16 + (lane & 15);                  // mem slot
    int k = KS * 32 + ((lane >> 4) << 3) + j;      // key col
    float v = 0.f;
    if (n < MEM) {
      int rk = ranks[n];
      v = (rk < BS) ? pk[(size_t)rk * KEY + k] : memK[(size_t)n * KEY + k];
    }
    keysF[id] = (_Float16)v;
  } else {
    int h = id - 65536;
    int j = h & 7, lane = (h >> 3) & 63, KS = (h >> 9) & 31, F = h >> 14;
    int nv = F * 16 + (lane & 15);                 // val col
    // permuted slot within the 32-slot k-step (see header comment)
    int jm = KS * 32 + ((j >> 2) << 4) + (((lane >> 4)) << 2) + (j & 3);
    float v = 0.f;
    if (jm < MEM) {
      int rk = ranks[jm];
      v = (rk < BS) ? pv[(size_t)rk * VAL + nv] : memV[(size_t)jm * VAL + nv];
    }
    valF[h] = (_Float16)v;
  }
}

// ---------------------------------------------------------------------------
// fused: features + attention + controller, 16 queries/wave (ONE tile),
// 8 waves/block (512 thr), grid 512 -> two sequential 1-block/CU rounds.
// Swapped-QK register softmax (R5) with register footprint sized for the
// allocator's ~128 arch-VGPR split (R6 lesson): O[8]+pq(8)+S[8] transient
// ~= 100 peak. qf frags stashed in loop-dead P_s LDS.
// ---------------------------------------------------------------------------

// softmax + PV for one tile, everything in registers.
#define SM_PV(S, rm, rl, O, Vc, c)                                          \
  {                                                                         \
    float cm = NEGF;                                                        \
    _Pragma("unroll")                                                       \
    for (int f = 0; f < 8; ++f) {                                           \
      const int sb = (c) * 128 + f * 16 + quad * 4;                         \
      _Pragma("unroll")                                                     \
      for (int r = 0; r < 4; ++r) {                                         \
        float s = (sb + r < MEM) ? S[f][r] : NEGF;                          \
        S[f][r] = s;                                                        \
        cm = fmaxf(cm, s);                                                  \
      }                                                                     \
    }                                                                       \
    cm = fmaxf(cm, __shfl_xor(cm, 16));                                     \
    cm = fmaxf(cm, __shfl_xor(cm, 32));                                     \
    float mn = fmaxf(rm, cm);                                               \
    float al = __expf(rm - mn);                                             \
    rm = mn;                                                                \
    float psl = 0.f;                                                        \
    _Pragma("unroll")                                                       \
    for (int f = 0; f < 8; ++f)                                             \
      _Pragma("unroll")                                                     \
      for (int r = 0; r < 4; ++r) {                                         \
        float p = __expf(S[f][r] - mn);                                     \
        S[f][r] = p;                                                        \
        psl += p;                                                           \
      }                                                                     \
    rl = rl * al + psl;                                                     \
    float alO[4];                                                           \
    _Pragma("unroll")                                                       \
    for (int r = 0; r < 4; ++r) alO[r] = __shfl(al, quad * 4 + r);          \
    _Pragma("unroll")                                                       \
    for (int v = 0; v < 8; ++v)                                             \
      _Pragma("unroll")                                                     \
      for (int r = 0; r < 4; ++r) O[v][r] *= alO[r];                        \
    _Pragma("unroll")                                                       \
    for (int ks = 0; ks < 4; ++ks) {                                        \
      h8v a;                                                                \
      _Pragma("unroll")                                                     \
      for (int e = 0; e < 4; ++e) {                                         \
        a[e]     = (_Float16)S[2 * ks][e];                                  \
        a[e + 4] = (_Float16)S[2 * ks + 1][e];                              \
      }                                                                     \
      _Pragma("unroll")                                                     \
      for (int v = 0; v < 8; ++v) {                                         \
        h8v b = *(const h8v*)(Vc + (size_t)(v * 4 + ks) * 512 + lane * 8);  \
        O[v] = MFMA16(a, b, O[v]);                                          \
      }                                                                     \
    }                                                                       \
  }

__global__ __launch_bounds__(512, 2) void k_fused(
    const float* __restrict__ qx, const float* __restrict__ qy,
    const _Float16* __restrict__ WTf, const float* __restrict__ bcomb,
    const float* __restrict__ c1_b, const float* __restrict__ c2_b,
    const float* __restrict__ c3W, const float* __restrict__ c3b,
    const _Float16* __restrict__ c1F, const _Float16* __restrict__ c2F,
    const _Float16* __restrict__ keysF, const _Float16* __restrict__ valF,
    float* __restrict__ dout)
{
  // LDS union, 148 KB total:
  //  phase 1: [0,131072) = WTsh (128 KB); per-wave tbuf at wid*4352 (34 KB)
  //  phase 2: K[2] at 0 (2x16 KB), V[2] at 32768 (2x32 KB), Pwk at 98304 (52 KB)
  __shared__ __align__(16) char smem[151552];
  _Float16* const WTsh = (_Float16*)smem;
  _Float16* const K0   = (_Float16*)smem;                 // 8192 halves
  _Float16* const K1   = (_Float16*)(smem + 16384);
  _Float16* const V0   = (_Float16*)(smem + 32768);       // 16384 halves
  _Float16* const V1   = (_Float16*)(smem + 65536);

  const int tid  = threadIdx.x;
  const int wid  = tid >> 6;
  const int lane = tid & 63;
  const int quad = lane >> 4;
  const int l15  = lane & 15;

  _Float16* const P_s  = (_Float16*)(smem + 98304 + wid * 6656);  // 2176 halves
  _Float16* const h2_s = P_s + 2176;                              // 1152 halves

  const int tile = blockIdx.x * 8 + wid;       // ONE query tile per wave
  const int q0   = tile * 16;

  float* out_pred = dout + 1;
  float* out_ret  = dout + 1 + BQ;
  const f4v fz = {0.f, 0.f, 0.f, 0.f};

  // ================= phase 1: features =================
  #pragma unroll
  for (int i = 0; i < 16; ++i) {
    const int t = wid * 16 + i;
    gld16(WTf + (size_t)t * 512 + lane * 8, WTsh + t * 512);
  }
  asm volatile("s_waitcnt vmcnt(0)" ::: "memory");
  __syncthreads();

  f4v acc[8];
  #pragma unroll
  for (int f = 0; f < 8; ++f) acc[f] = fz;
  const float* xr = qx + (size_t)(q0 + l15) * DIN;

  #pragma unroll 4
  for (int ks = 0; ks < 16; ++ks) {
    const int k0 = ks * 32 + quad * 8;
    h8v a = cvt8nt(xr + k0);
    #pragma unroll
    for (int f = 0; f < 8; ++f) {
      h8v b = *(const h8v*)(WTsh + (size_t)((f * 16 + ks) * 64 + lane) * 8);
      acc[f] = MFMA16(a, b, acc[f]);
    }
  }
  __syncthreads();   // all waves done reading WTsh -> reuse as scratch

  // C-layout -> A-frag registers via per-wave LDS transpose.
  // qf frags go to the P_s stash (loop-dead LDS), NOT loop-long registers.
  _Float16* tbuf = (_Float16*)(smem + wid * 4352);  // 2176 halves
  h8v pq0, pq1;
  {
    #pragma unroll
    for (int f = 0; f < 8; ++f) {
      float bb = bcomb[f * 16 + l15];
      #pragma unroll
      for (int r = 0; r < 4; ++r)
        tbuf[(quad * 4 + r) * 136 + f * 16 + l15] = (_Float16)(acc[f][r] + bb);
    }
    h8v qf0 = *(const h8v*)&tbuf[l15 * 136 +  0 + quad * 8];
    h8v qf1 = *(const h8v*)&tbuf[l15 * 136 + 32 + quad * 8];
    pq0 = *(const h8v*)&tbuf[l15 * 136 + 64 + quad * 8];
    pq1 = *(const h8v*)&tbuf[l15 * 136 + 96 + quad * 8];
    *(h8v*)&P_s[0 * 512 + lane * 8] = qf0;
    *(h8v*)&P_s[1 * 512 + lane * 8] = qf1;
  }
  __syncthreads();   // scratch reads done -> K/V staging may overwrite

  // ================= phase 2: attention =================
  // stage chunk 0 (8 waves: 2 K-tiles + 4 V-tiles each)
  #pragma unroll
  for (int i = 0; i < 2; ++i) {
    const int t = wid * 2 + i;
    gld16(keysF + (size_t)t * 512 + lane * 8, K0 + t * 512);
  }
  #pragma unroll
  for (int i = 0; i < 4; ++i) {
    const int t = wid * 4 + i;
    const int v = t >> 2, sub = t & 3;
    gld16(valF + ((size_t)(v * 32 + sub)) * 512 + lane * 8,
          V0 + (v * 4 + sub) * 512);
  }
  asm volatile("s_waitcnt vmcnt(0)" ::: "memory");
  __syncthreads();

  float rm = NEGF, rl = 0.f;                   // scalars (query = l15)
  f4v O[8];
  #pragma unroll
  for (int v = 0; v < 8; ++v) O[v] = fz;

  #pragma unroll 1
  for (int c = 0; c < 8; ++c) {
    const int cur = c & 1;
    _Float16* const Kc = cur ? K1 : K0;
    _Float16* const Vc = cur ? V1 : V0;
    _Float16* const Kn = cur ? K0 : K1;
    _Float16* const Vn = cur ? V0 : V1;

    // prefetch next chunk (or c1F into the dying buffer pair at c==7)
    if (c < 7) {
      const int nc = c + 1;
      const _Float16* kc = keysF + (size_t)nc * 8192;
      #pragma unroll
      for (int i = 0; i < 2; ++i) {
        const int t = wid * 2 + i;
        gld16(kc + (size_t)t * 512 + lane * 8, Kn + t * 512);
      }
      #pragma unroll
      for (int i = 0; i < 4; ++i) {
        const int t = wid * 4 + i;
        const int v = t >> 2, sub = t & 3;
        gld16(valF + ((size_t)(v * 32 + nc * 4 + sub)) * 512 + lane * 8,
              Vn + (v * 4 + sub) * 512);
      }
    } else {
      // c1F: 48 x 1 KB tiles -> K0(16) + V0(32); 6 tiles per wave
      #pragma unroll
      for (int i = 0; i < 6; ++i) {
        const int t = wid * 6 + i;
        _Float16* dst = (t < 16) ? (K0 + t * 512) : (V0 + (t - 16) * 512);
        gld16(c1F + (size_t)t * 512 + lane * 8, dst);
      }
    }

    // ---- QK^T (swapped) -> softmax + PV (register-only) ----
    {
      f4v S[8];
      #pragma unroll
      for (int f = 0; f < 8; ++f) S[f] = fz;
      #pragma unroll
      for (int f = 0; f < 8; ++f) {
        h8v b0 = *(const h8v*)(Kc + (size_t)(f * 2 + 0) * 512 + lane * 8);
        h8v b1 = *(const h8v*)(Kc + (size_t)(f * 2 + 1) * 512 + lane * 8);
        S[f] = MFMA16(b0, pq0, S[f]);
        S[f] = MFMA16(b1, pq1, S[f]);
      }
      SM_PV(S, rm, rl, O, Vc, c)
    }

    // drain next-chunk staging + protect buffer reuse across all 8 waves
    asm volatile("s_waitcnt vmcnt(0)" ::: "memory");
    __syncthreads();
  }

  // ---- final denominator: reduce over quads, redistribute to O layout ----
  rl += __shfl_xor(rl, 16); rl += __shfl_xor(rl, 32);
  float rlO[4];
  #pragma unroll
  for (int r = 0; r < 4; ++r) rlO[r] = __shfl(rl, quad * 4 + r);

  // reload stashed qf BEFORE ret writes clobber P_s
  h8v qf0 = *(const h8v*)&P_s[0 * 512 + lane * 8];
  h8v qf1 = *(const h8v*)&P_s[1 * 512 + lane * 8];

  // ================= phase 3: epilogue =================
  // retrieved -> LDS fp16
  #pragma unroll
  for (int v = 0; v < 8; ++v)
    #pragma unroll
    for (int r = 0; r < 4; ++r)
      P_s[(quad * 4 + r) * 136 + v * 16 + l15] = (_Float16)(O[v][r] / rlO[r]);

  // contiguous nt stores: 8 iters x (64 lanes x 16 B)
  #pragma unroll
  for (int it = 0; it < 8; ++it) {
    int flat = it * 256 + lane * 4;
    int row = flat >> 7, col = flat & 127;
    h4v t = *(const h4v*)&P_s[row * 136 + col];
    f4v o;
    o.x = (float)t[0]; o.y = (float)t[1]; o.z = (float)t[2]; o.w = (float)t[3];
    __builtin_nontemporal_store(o, (f4v*)(out_ret + (size_t)q0 * VAL + flat));
  }

  // c1: relu([qf|ret] @ c1_W + b); b-frags from LDS (staged at c==7)
  {
    f4v H[8];
    #pragma unroll
    for (int f = 0; f < 8; ++f) H[f] = fz;
    #pragma unroll
    for (int ks = 0; ks < 6; ++ks) {
      const int k0 = ks * 32;
      h8v a = (ks == 0) ? qf0 : (ks == 1) ? qf1
               : *(const h8v*)&P_s[l15 * 136 + (k0 - 64) + quad * 8];
      #pragma unroll
      for (int f = 0; f < 8; ++f) {
        const int t = f * 6 + ks;
        const _Float16* bp = (t < 16) ? (K0 + (size_t)t * 512)
                                      : (V0 + (size_t)(t - 16) * 512);
        h8v b = *(const h8v*)(bp + lane * 8);
        H[f] = MFMA16(a, b, H[f]);
      }
    }
    #pragma unroll
    for (int f = 0; f < 8; ++f) {
      float bb = c1_b[f * 16 + l15];
      #pragma unroll
      for (int r = 0; r < 4; ++r)
        P_s[(quad * 4 + r) * 136 + f * 16 + l15] =
            (_Float16)fmaxf(0.f, H[f][r] + bb);
    }
  }

  // c2: relu(h1 @ c2_W + b) -> h2
  {
    f4v G[4];
    #pragma unroll
    for (int f = 0; f < 4; ++f) G[f] = fz;
    #pragma unroll
    for (int ks = 0; ks < 4; ++ks) {
      h8v a = *(const h8v*)&P_s[l15 * 136 + ks * 32 + quad * 8];
      #pragma unroll
      for (int f = 0; f < 4; ++f) {
        h8v b = *(const h8v*)(c2F + (size_t)(f * 4 + ks) * 512 + lane * 8);
        G[f] = MFMA16(a, b, G[f]);
      }
    }
    #pragma unroll
    for (int f = 0; f < 4; ++f) {
      float bb = c2_b[f * 16 + l15];
      #pragma unroll
      for (int r = 0; r < 4; ++r)
        h2_s[(quad * 4 + r) * 72 + f * 16 + l15] =
            (_Float16)fmaxf(0.f, G[f][r] + bb);
    }
  }

  // c3 + loss (4 lanes per query row)
  float lsum;
  {
    const int prow = lane >> 2, pj = lane & 3;
    float s = 0.f;
    #pragma unroll
    for (int k = 0; k < 16; ++k) {
      int kk = pj * 16 + k;
      s += (float)h2_s[prow * 72 + kk] * c3W[kk];
    }
    s += __shfl_xor(s, 1);
    s += __shfl_xor(s, 2);
    float pred = s + c3b[0];
    float diff = pred - qy[q0 + prow];
    if (pj == 0) out_pred[q0 + prow] = pred;
    lsum = diff * diff;                        // each row counted 4x
  }
  #pragma unroll
  for (int m = 1; m < 64; m <<= 1) lsum += __shfl_xor(lsum, m);
  if (lane == 0) atomicAdd(dout, lsum * (1.0f / (4.0f * (float)BQ)));
}

// ---------------------------------------------------------------------------
extern "C" void kernel_launch(void* const* d_in, const int* in_sizes, int n_in,
                              void* d_out, int out_size, void* d_ws, size_t ws_size,
                              hipStream_t stream)
{
  const float* support_x = (const float*)d_in[0];
  const float* support_y = (const float*)d_in[1];
  const float* query_x   = (const float*)d_in[2];
  const float* query_y   = (const float*)d_in[3];
  const float* base_W    = (const float*)d_in[4];
  const float* base_b    = (const float*)d_in[5];
  const float* kp_W      = (const float*)d_in[6];
  const float* kp_b      = (const float*)d_in[7];
  const float* vp_W      = (const float*)d_in[8];
  const float* vp_b      = (const float*)d_in[9];
  const float* mem_keys  = (const float*)d_in[10];
  const float* mem_vals  = (const float*)d_in[11];
  const float* mem_age   = (const float*)d_in[12];
  const float* c1_W      = (const float*)d_in[13];
  const float* c1_b      = (const float*)d_in[14];
  const float* c2_W      = (const float*)d_in[15];
  const float* c2_b      = (const float*)d_in[16];
  const float* c3_W      = (const float*)d_in[17];
  const float* c3_b      = (const float*)d_in[18];

  char* w = (char*)d_ws;                        // ~1 MB used
  _Float16* WTf   = (_Float16*)(w + 0);         // 128 KB fragment-major
  _Float16* vpWt  = (_Float16*)(w + 131072);    // 32 KB
  _Float16* c1F   = (_Float16*)(w + 163840);    // 48 KB fragment-major
  _Float16* c2F   = (_Float16*)(w + 212992);    // 16 KB fragment-major
  float*    bcomb = (float*)   (w + 229376);    // 512 B
  int*      ranks = (int*)     (w + 229888);    // 4 KB
  float*    pkeys = (float*)   (w + 233984);    // 128 KB
  float*    pvals = (float*)   (w + 365056);    // 256 KB
  _Float16* keysF = (_Float16*)(w + 627200);    // 128 KB fragment-major
  _Float16* valF  = (_Float16*)(w + 758272);    // 256 KB fragment-major

  float* out = (float*)d_out;

  hipLaunchKernelGGL(k_prep1, dim3(453), dim3(256), 0, stream,
                     base_W, base_b, kp_W, kp_b, vp_W, c1_W, c2_W, mem_age,
                     WTf, bcomb, vpWt, c1F, c2F, ranks, out);
  hipLaunchKernelGGL(k_prep2, dim3(64), dim3(64), 0, stream,
                     support_x, support_y, WTf, bcomb, vpWt, vp_b, pkeys, pvals);
  hipLaunchKernelGGL(k_prep3, dim3(768), dim3(256), 0, stream,
                     ranks, pkeys, pvals, mem_keys, mem_vals, keysF, valF);
  hipLaunchKernelGGL(k_fused, dim3(BQ / 128), dim3(512), 0, stream,
                     query_x, query_y, WTf, bcomb, c1_b, c2_b, c3_W, c3_b,
                     c1F, c2F, keysF, valF, out);
}